// Round 2
// baseline (495.288 us; speedup 1.0000x reference)
//
#include <hip/hip_runtime.h>

// ---- types ----
typedef float    f32x4 __attribute__((ext_vector_type(4)));
typedef _Float16 f16x8 __attribute__((ext_vector_type(8)));

#define TM 128
#define TN 128
#define TK 32

// async global->LDS, 16B per lane (dest must be wave-uniform base + lane*16)
__device__ __forceinline__ void gload16(const void* g, void* l) {
  __builtin_amdgcn_global_load_lds(
      (__attribute__((address_space(1))) void*)(const void*)g,
      (__attribute__((address_space(3))) void*)l,
      16, 0, 0);
}

// ---- generic BT-GEMM: D = A(MxK) * B(NxK)^T, fp16 in, fp32 acc ----
// EPI 0: out1(f16) = acc (+ bias[col] if bias)            [proj k/q, FFN1]
// EPI 2: pv = acc + resid; out0(f32)=pv; out1(f16)=pv     [PV residual]
// EPI 3: out0(f32) = resid + relu(acc)                    [final]
// EPI 4: per-column softmax partial stats -> out0(m), out2(Z); no S store
// EPI 5: out1(f16) = exp(acc - bias[b*2048+col]) * resid[b*2048+col]  [P]
template <int EPI>
__global__ __launch_bounds__(256) void gemm_bt(
    const _Float16* __restrict__ A, size_t sA, int lda,
    const _Float16* __restrict__ B, size_t sB, int ldb,
    float* __restrict__ out0, _Float16* __restrict__ out1,
    float* __restrict__ out2,
    size_t sO, int ldo,
    const float* __restrict__ bias,
    const float* __restrict__ resid,
    int K) {
  __shared__ _Float16 As[TM * TK];
  __shared__ _Float16 Bs[TN * TK];
  const int b  = blockIdx.z;
  const int m0 = blockIdx.y * TM;
  const int n0 = blockIdx.x * TN;
  const _Float16* Ab = A + (size_t)b * sA;
  const _Float16* Bb = B + (size_t)b * sB;
  const int t    = threadIdx.x;
  const int lane = t & 63;
  const int w    = t >> 6, wr = w >> 1, wc = w & 1;  // 2x2 wave grid, 64x64 each
  const int lr   = lane & 15, lq = lane >> 4;

  f32x4 acc[4][4];
#pragma unroll
  for (int i = 0; i < 4; ++i)
#pragma unroll
    for (int j = 0; j < 4; ++j) acc[i][j] = (f32x4){0.f, 0.f, 0.f, 0.f};

  // staging: tile is [128 rows][32 k] f16 = 8KB = 512 x 16B segs; 2 per thread
  const int s0 = t, s1 = t + 256;
  const int r0 = s0 >> 2, c0 = (s0 & 3) * 8;
  const int r1 = s1 >> 2, c1 = (s1 & 3) * 8;

  for (int k0 = 0; k0 < K; k0 += TK) {
    __syncthreads();
    gload16(Ab + (size_t)(m0 + r0) * lda + k0 + c0, As + s0 * 8);
    gload16(Ab + (size_t)(m0 + r1) * lda + k0 + c1, As + s1 * 8);
    gload16(Bb + (size_t)(n0 + r0) * ldb + k0 + c0, Bs + s0 * 8);
    gload16(Bb + (size_t)(n0 + r1) * ldb + k0 + c1, Bs + s1 * 8);
    __syncthreads();
    f16x8 af[4], bf[4];
#pragma unroll
    for (int i = 0; i < 4; ++i) af[i] = *(const f16x8*)&As[(wr * 64 + i * 16 + lr) * TK + lq * 8];
#pragma unroll
    for (int j = 0; j < 4; ++j) bf[j] = *(const f16x8*)&Bs[(wc * 64 + j * 16 + lr) * TK + lq * 8];
#pragma unroll
    for (int i = 0; i < 4; ++i)
#pragma unroll
      for (int j = 0; j < 4; ++j)
        acc[i][j] = __builtin_amdgcn_mfma_f32_16x16x32_f16(af[i], bf[j], acc[i][j], 0, 0, 0);
  }

  if constexpr (EPI == 4) {
    // per-column online (max, sumexp) over this wave's 64-row stripe
#pragma unroll
    for (int j = 0; j < 4; ++j) {
      float m = -3.4e38f;
#pragma unroll
      for (int i = 0; i < 4; ++i)
#pragma unroll
        for (int r = 0; r < 4; ++r) m = fmaxf(m, acc[i][j][r]);
      float Z = 0.f;
#pragma unroll
      for (int i = 0; i < 4; ++i)
#pragma unroll
        for (int r = 0; r < 4; ++r) Z += __expf(acc[i][j][r] - m);
      // combine across the 4 lanes (lq = lane>>4) sharing each column
#pragma unroll
      for (int d = 16; d <= 32; d <<= 1) {
        float mo = __shfl_xor(m, d, 64);
        float Zo = __shfl_xor(Z, d, 64);
        float mn = fmaxf(m, mo);
        Z = Z * __expf(m - mn) + Zo * __expf(mo - mn);
        m = mn;
      }
      if (lq == 0) {
        const int chunk = blockIdx.y * 2 + wr;  // 32 chunks of 64 rows
        const size_t sidx = ((size_t)b * 32 + chunk) * 2048 + n0 + wc * 64 + j * 16 + lr;
        out0[sidx] = m;
        out2[sidx] = Z;
      }
    }
  } else {
    // D frag: col = lane&15, row = (lane>>4)*4 + r
#pragma unroll
    for (int i = 0; i < 4; ++i)
#pragma unroll
      for (int j = 0; j < 4; ++j)
#pragma unroll
        for (int r = 0; r < 4; ++r) {
          const int row = m0 + wr * 64 + i * 16 + lq * 4 + r;
          const int col = n0 + wc * 64 + j * 16 + lr;
          const size_t oidx = (size_t)b * sO + (size_t)row * ldo + col;
          float v = acc[i][j][r];
          if constexpr (EPI == 0) {
            if (bias) v += bias[col];
            out1[oidx] = (_Float16)v;
          } else if constexpr (EPI == 2) {
            const float pv = v + resid[oidx];
            out0[oidx] = pv;
            out1[oidx] = (_Float16)pv;
          } else if constexpr (EPI == 3) {
            out0[oidx] = resid[oidx] + (v > 0.f ? v : 0.f);
          } else {  // EPI == 5
            const size_t cidx = (size_t)b * 2048 + col;
            out1[oidx] = (_Float16)(__expf(v - bias[cidx]) * resid[cidx]);
          }
        }
  }
}

// ---- fp32 -> fp16 convert, 8 elems/thread ----
__global__ __launch_bounds__(256) void convert_f32_f16(const float* __restrict__ in,
                                                       _Float16* __restrict__ out, long n8) {
  long i = (long)blockIdx.x * blockDim.x + threadIdx.x;
  if (i >= n8) return;
  f32x4 v0 = *(const f32x4*)(in + i * 8);
  f32x4 v1 = *(const f32x4*)(in + i * 8 + 4);
  f16x8 o;
  o[0] = (_Float16)v0[0]; o[1] = (_Float16)v0[1]; o[2] = (_Float16)v0[2]; o[3] = (_Float16)v0[3];
  o[4] = (_Float16)v1[0]; o[5] = (_Float16)v1[1]; o[6] = (_Float16)v1[2]; o[7] = (_Float16)v1[3];
  *(f16x8*)(out + i * 8) = o;
}

// ---- combine 32 row-chunk partials per column -> m_final, 1/Z ----
__global__ __launch_bounds__(256) void col_final(const float* __restrict__ pm,
                                                 const float* __restrict__ pZ,
                                                 float* __restrict__ mfin,
                                                 float* __restrict__ rZ) {
  const int b = blockIdx.z;
  const int c = blockIdx.x * 256 + threadIdx.x;
  float m = -3.4e38f;
  for (int k = 0; k < 32; ++k) m = fmaxf(m, pm[((size_t)b * 32 + k) * 2048 + c]);
  float Z = 0.f;
  for (int k = 0; k < 32; ++k) {
    const size_t idx = ((size_t)b * 32 + k) * 2048 + c;
    Z += pZ[idx] * __expf(pm[idx] - m);
  }
  mfin[(size_t)b * 2048 + c] = m;
  rZ[(size_t)b * 2048 + c]   = 1.f / Z;
}

// ---- x[b][j][c] (f32) -> xT[b][c][j] (f16), 32x32 LDS tile ----
__global__ void transpose_f32_to_f16(const float* __restrict__ x, _Float16* __restrict__ xT) {
  __shared__ float tile[32][33];
  const int b = blockIdx.z;
  const int c0 = blockIdx.x * 32, j0 = blockIdx.y * 32;
  const float* xb  = x  + (size_t)b * 2048 * 768;
  _Float16*    xTb = xT + (size_t)b * 768 * 2048;
  const int tx = threadIdx.x, ty = threadIdx.y;
#pragma unroll
  for (int dy = 0; dy < 32; dy += 8)
    tile[ty + dy][tx] = xb[(size_t)(j0 + ty + dy) * 768 + c0 + tx];
  __syncthreads();
#pragma unroll
  for (int dy = 0; dy < 32; dy += 8)
    xTb[(size_t)(c0 + ty + dy) * 2048 + j0 + tx] = (_Float16)tile[tx][ty + dy];
}

extern "C" void kernel_launch(void* const* d_in, const int* in_sizes, int n_in,
                              void* d_out, int out_size, void* d_ws, size_t ws_size,
                              hipStream_t stream) {
  const float* x  = (const float*)d_in[0];
  const float* Wk = (const float*)d_in[1];
  const float* bk = (const float*)d_in[2];
  const float* Wq = (const float*)d_in[3];
  const float* bq = (const float*)d_in[4];
  const float* W1 = (const float*)d_in[5];
  const float* W2 = (const float*)d_in[6];
  float* out = (float*)d_out;

  // ---- ws layout (~193 MiB peak) ----
  char* ws = (char*)d_ws;
  size_t off = 0;
  auto alloc = [&](size_t bytes) -> char* {
    char* p = ws + off;
    off += (bytes + 255) & ~(size_t)255;
    return p;
  };
  _Float16* xf = (_Float16*)alloc(25165824);   // x_f16; reused as xT
  _Float16* kf = (_Float16*)alloc(25165824);   // k;     reused as p_f16
  _Float16* qf = (_Float16*)alloc(25165824);   // q;     reused as h_f16
  _Float16* Wf = (_Float16*)alloc(4718592);    // Wk,Wq,W1,W2 f16
  _Float16* P  = (_Float16*)alloc(67108864);   // attn f16
  float*    pf32 = (float*)alloc(50331648);    // p f32 (residual for final)
  float*    pm = (float*)alloc(2097152);       // [8][32][2048] partial max
  float*    pZ = (float*)alloc(2097152);       // [8][32][2048] partial sumexp
  float*    mfin = (float*)alloc(65536);
  float*    rZ   = (float*)alloc(65536);

  _Float16* Wkf = Wf;
  _Float16* Wqf = Wf + 589824;
  _Float16* W1f = Wf + 2 * 589824;
  _Float16* W2f = Wf + 3 * 589824;
  _Float16* xT   = xf;  // alias: valid after proj GEMMs consumed x_f16
  _Float16* pf16 = kf;  // alias: valid after P pass consumed k
  _Float16* hf16 = qf;  // alias: valid after P pass consumed q

  const size_t sKV = (size_t)2048 * 768;   // per-batch k/q/p stride
  const size_t sS  = (size_t)2048 * 2048;  // per-batch score/P stride

  // 1. converts
  convert_f32_f16<<<6144, 256, 0, stream>>>(x,  xf,  1572864);
  convert_f32_f16<<<288,  256, 0, stream>>>(Wk, Wkf, 73728);
  convert_f32_f16<<<288,  256, 0, stream>>>(Wq, Wqf, 73728);
  convert_f32_f16<<<288,  256, 0, stream>>>(W1, W1f, 73728);
  convert_f32_f16<<<288,  256, 0, stream>>>(W2, W2f, 73728);

  // 2. projections: k, q  (M=16384, N=768, K=768)
  dim3 gProj(6, 128, 1);
  gemm_bt<0><<<gProj, 256, 0, stream>>>(xf, 0, 768, Wkf, 0, 768,
                                        nullptr, kf, nullptr, 0, 768, bk, nullptr, 768);
  gemm_bt<0><<<gProj, 256, 0, stream>>>(xf, 0, 768, Wqf, 0, 768,
                                        nullptr, qf, nullptr, 0, 768, bq, nullptr, 768);

  // 3. xT (overwrites x_f16 — proj GEMMs already done)
  transpose_f32_to_f16<<<dim3(24, 64, 8), dim3(32, 8), 0, stream>>>(x, xT);

  // 4. stats pass: S[b] = k_b * q_b^T, reduce per-column (m, Z), no S store
  dim3 gS(16, 16, 8);
  gemm_bt<4><<<gS, 256, 0, stream>>>(kf, sKV, 768, qf, sKV, 768,
                                     pm, nullptr, pZ, 0, 0, nullptr, nullptr, 768);
  col_final<<<dim3(8, 1, 8), 256, 0, stream>>>(pm, pZ, mfin, rZ);

  // 5. P pass: recompute S, write P = exp(S - m_col) * rZ_col (f16)
  gemm_bt<5><<<gS, 256, 0, stream>>>(kf, sKV, 768, qf, sKV, 768,
                                     nullptr, P, nullptr, sS, 2048, mfin, rZ, 768);

  // 6. PV: p = x + P_b * x_b  (M=2048, N=768, K=2048), dual f32/f16 out
  dim3 gPV(6, 16, 8);
  gemm_bt<2><<<gPV, 256, 0, stream>>>(P, sS, 2048, xT, sKV, 2048,
                                      pf32, pf16, nullptr, sKV, 768,
                                      nullptr, x, 2048);

  // 7. FFN1: h = p * W1^T (f16 out)
  gemm_bt<0><<<gProj, 256, 0, stream>>>(pf16, 0, 768, W1f, 0, 768,
                                        nullptr, hf16, nullptr, 0, 768, nullptr, nullptr, 768);

  // 8. FFN2 + residual + relu: out = p + relu(h * W2^T)
  gemm_bt<3><<<gProj, 256, 0, stream>>>(hf16, 0, 768, W2f, 0, 768,
                                        out, nullptr, nullptr, 0, 768, nullptr, pf32, 768);
}

// Round 3
// 385.830 us; speedup vs baseline: 1.2837x; 1.2837x over previous
//
#include <hip/hip_runtime.h>

typedef float    f32x4 __attribute__((ext_vector_type(4)));
typedef _Float16 f16x8 __attribute__((ext_vector_type(8)));

// async global->LDS, 16B per lane (dest = wave-uniform base + lane*16)
__device__ __forceinline__ void gload16(const void* g, void* l) {
  __builtin_amdgcn_global_load_lds(
      (__attribute__((address_space(1))) void*)(const void*)g,
      (__attribute__((address_space(3))) void*)l,
      16, 0, 0);
}

// ===================== 256x256 phase-split BT-GEMM engine =====================
// D = A(MxK) * B(NxK)^T, f16 in, f32 acc. 512 threads = 8 waves (2M x 4N),
// per-wave 128x64 output = acc[8][4] f32x4. BK=32, 3 LDS buffers (96KB),
// staging 2 tiles ahead, per-tile wait = vmcnt(4) (counted, never drains
// mid-loop). Need-based staging: wave (wr,wch) stages exactly A-half(wr),
// B-half(wch). LDS XOR swizzle slot^=(row>>1)&3 on source + read.
// EPI 0: out1(f16) = acc (+ bias[col])                      [proj, FFN1]
// EPI 2: pv = acc + resid; out0(f32)=pv; out1(f16)=pv       [PV residual]
// EPI 3: out0(f32) = resid + relu(acc)                      [final]
// EPI 4: per-column (m,Z) partials -> out0, out2 (16 chunks of 128 rows)
// EPI 5: out1(f16) = exp(acc - bias[b*2048+col]) * resid[b*2048+col]  [P]
template <int EPI>
__global__ __launch_bounds__(512, 2) void gemm256(
    const _Float16* __restrict__ A, size_t sA, int lda,
    const _Float16* __restrict__ B, size_t sB, int ldb,
    float* __restrict__ out0, _Float16* __restrict__ out1,
    float* __restrict__ out2,
    size_t sO, int ldo,
    const float* __restrict__ bias,
    const float* __restrict__ resid,
    int K) {
  __shared__ _Float16 lds[3 * 16384];  // 3 bufs x (A[2][128][32] + B[2][128][32])

  // ---- XCD-bijective block swizzle over flattened grid ----
  const int gx = gridDim.x, gy = gridDim.y;
  const int nblk = gx * gy * gridDim.z;
  int lin = (blockIdx.z * gy + blockIdx.y) * gx + blockIdx.x;
  if (!(nblk & 7)) lin = (lin & 7) * (nblk >> 3) + (lin >> 3);
  const int b  = lin / (gx * gy);
  const int r2 = lin - b * gx * gy;
  const int m0 = (r2 / gx) * 256;
  const int n0 = (r2 - (r2 / gx) * gx) * 256;

  const int t = threadIdx.x, lane = t & 63, w = t >> 6;
  const int wr = w >> 2;          // wave M-half (0/1): rows m0+wr*128..+127
  const int wc = w & 3;           // wave N-quarter: cols n0+wc*64..+63
  const int wch = (w >> 1) & 1;   // wave B-half
  const int lr = lane & 15, lq = lane >> 4;

  const _Float16* Ab = A + (size_t)b * sA;
  const _Float16* Bb = B + (size_t)b * sB;

  // ---- staging descriptors (need-based groups of 4 waves) ----
  const int ga = (w & 3) * 64 + lane;                  // 0..255 within A-group
  const int gb = (((w >> 2) << 1) | (w & 1)) * 64 + lane;  // 0..255 within B-group
  // seg -> (row, swizzled col): row=s>>2, col=((s&3)^((s>>3)&3))*8 elements
  const int ra0 = ga >> 2,          ca0 = ((ga & 3) ^ ((ga >> 3) & 3)) * 8;
  const int ra1 = (ga + 256) >> 2,  ca1 = (((ga + 256) & 3) ^ (((ga + 256) >> 3) & 3)) * 8;
  const int rb0 = gb >> 2,          cb0 = ((gb & 3) ^ ((gb >> 3) & 3)) * 8;
  const int rb1 = (gb + 256) >> 2,  cb1 = (((gb + 256) & 3) ^ (((gb + 256) >> 3) & 3)) * 8;
  const _Float16* a_src0 = Ab + (size_t)(m0 + wr * 128 + ra0) * lda + ca0;
  const _Float16* a_src1 = Ab + (size_t)(m0 + wr * 128 + ra1) * lda + ca1;
  const _Float16* b_src0 = Bb + (size_t)(n0 + wch * 128 + rb0) * ldb + cb0;
  const _Float16* b_src1 = Bb + (size_t)(n0 + wch * 128 + rb1) * ldb + cb1;
  const int a_dst = wr * 4096 + ga * 8;            // A area at +0
  const int b_dst = 8192 + wch * 4096 + gb * 8;    // B area at +8192

  // ---- ds_read bases (swizzled) ----
  const int swz  = ((lr >> 1) & 3) << 3;  // f16 units
  const int a_rd = wr * 4096 + lr * 32 + ((lq * 8) ^ swz);                    // + f*512
  const int b_rd = 8192 + wch * 4096 + ((wc & 1) * 64 + lr) * 32 + ((lq * 8) ^ swz);  // + j*512

  f32x4 acc[8][4];
#pragma unroll
  for (int f = 0; f < 8; ++f)
#pragma unroll
    for (int j = 0; j < 4; ++j) acc[f][j] = (f32x4){0.f, 0.f, 0.f, 0.f};

  const int NT = K >> 5;  // BK=32 tiles

  // ---- prologue: stage tiles 0 and 1 ----
  {
    _Float16* l0 = lds;
    gload16(a_src0, l0 + a_dst);
    gload16(a_src1, l0 + a_dst + 2048);
    gload16(b_src0, l0 + b_dst);
    gload16(b_src1, l0 + b_dst + 2048);
    _Float16* l1 = lds + 16384;
    gload16(a_src0 + 32, l1 + a_dst);
    gload16(a_src1 + 32, l1 + a_dst + 2048);
    gload16(b_src0 + 32, l1 + b_dst);
    gload16(b_src1 + 32, l1 + b_dst + 2048);
  }

  int buf = 0;
  for (int kt = 0; kt < NT; ++kt) {
    // tile boundary: my group's loads for tile kt are my oldest; leave the
    // next tile's 4 in flight (counted vmcnt — T4). Last tile: full drain.
    if (kt + 1 < NT) asm volatile("s_waitcnt vmcnt(4)" ::: "memory");
    else             asm volatile("s_waitcnt vmcnt(0)" ::: "memory");
    __builtin_amdgcn_s_barrier();        // join all staging groups
    __builtin_amdgcn_sched_barrier(0);   // nothing moves above this point

    const _Float16* lb = lds + buf * 16384;
    const int nb = (buf + 2 >= 3) ? buf - 1 : buf + 2;
    _Float16* ln = lds + nb * 16384;
    const int ko = (kt + 2) * 32;
    const bool st = (kt + 2 < NT);

    // ---- phase 0: A frags + B frags 0,1 ; stage A-pair of tile kt+2 ----
    f16x8 af[8], bf[4];
#pragma unroll
    for (int f = 0; f < 8; ++f) af[f] = *(const f16x8*)(lb + a_rd + f * 512);
    bf[0] = *(const f16x8*)(lb + b_rd);
    bf[1] = *(const f16x8*)(lb + b_rd + 512);
    if (st) {
      gload16(a_src0 + ko, ln + a_dst);
      gload16(a_src1 + ko, ln + a_dst + 2048);
    }
    __builtin_amdgcn_sched_barrier(0);
    __builtin_amdgcn_s_barrier();
    __builtin_amdgcn_s_setprio(1);
#pragma unroll
    for (int f = 0; f < 8; ++f) {
      acc[f][0] = __builtin_amdgcn_mfma_f32_16x16x32_f16(af[f], bf[0], acc[f][0], 0, 0, 0);
      acc[f][1] = __builtin_amdgcn_mfma_f32_16x16x32_f16(af[f], bf[1], acc[f][1], 0, 0, 0);
    }
    __builtin_amdgcn_s_setprio(0);
    __builtin_amdgcn_s_barrier();

    // ---- phase 1: B frags 2,3 ; stage B-pair of tile kt+2 ----
    bf[2] = *(const f16x8*)(lb + b_rd + 1024);
    bf[3] = *(const f16x8*)(lb + b_rd + 1536);
    if (st) {
      gload16(b_src0 + ko, ln + b_dst);
      gload16(b_src1 + ko, ln + b_dst + 2048);
    }
    __builtin_amdgcn_sched_barrier(0);
    __builtin_amdgcn_s_barrier();
    __builtin_amdgcn_s_setprio(1);
#pragma unroll
    for (int f = 0; f < 8; ++f) {
      acc[f][2] = __builtin_amdgcn_mfma_f32_16x16x32_f16(af[f], bf[2], acc[f][2], 0, 0, 0);
      acc[f][3] = __builtin_amdgcn_mfma_f32_16x16x32_f16(af[f], bf[3], acc[f][3], 0, 0, 0);
    }
    __builtin_amdgcn_s_setprio(0);
    __builtin_amdgcn_s_barrier();

    buf = (buf + 1 >= 3) ? 0 : buf + 1;
  }

  // ---- epilogues. D frag: col = lr, row = lq*4 + r ----
  if constexpr (EPI == 4) {
#pragma unroll
    for (int j = 0; j < 4; ++j) {
      float m = -3.4e38f;
#pragma unroll
      for (int f = 0; f < 8; ++f)
#pragma unroll
        for (int r = 0; r < 4; ++r) m = fmaxf(m, acc[f][j][r]);
      float Z = 0.f;
#pragma unroll
      for (int f = 0; f < 8; ++f)
#pragma unroll
        for (int r = 0; r < 4; ++r) Z += __expf(acc[f][j][r] - m);
      // combine across the 4 lq lanes sharing each column
#pragma unroll
      for (int d = 16; d <= 32; d <<= 1) {
        float mo = __shfl_xor(m, d, 64);
        float Zo = __shfl_xor(Z, d, 64);
        float mn = fmaxf(m, mo);
        Z = Z * __expf(m - mn) + Zo * __expf(mo - mn);
        m = mn;
      }
      if (lq == 0) {
        const int chunk = (m0 >> 7) + wr;  // 128-row chunks, 16 per batch
        const int col = n0 + wc * 64 + j * 16 + lr;
        const size_t sidx = ((size_t)b * 16 + chunk) * 2048 + col;
        out0[sidx] = m;
        out2[sidx] = Z;
      }
    }
  } else {
#pragma unroll
    for (int f = 0; f < 8; ++f)
#pragma unroll
      for (int j = 0; j < 4; ++j)
#pragma unroll
        for (int r = 0; r < 4; ++r) {
          const int row = m0 + wr * 128 + f * 16 + lq * 4 + r;
          const int col = n0 + wc * 64 + j * 16 + lr;
          const size_t oidx = (size_t)b * sO + (size_t)row * ldo + col;
          float v = acc[f][j][r];
          if constexpr (EPI == 0) {
            if (bias) v += bias[col];
            out1[oidx] = (_Float16)v;
          } else if constexpr (EPI == 2) {
            const float pv = v + resid[oidx];
            out0[oidx] = pv;
            out1[oidx] = (_Float16)pv;
          } else if constexpr (EPI == 3) {
            out0[oidx] = resid[oidx] + (v > 0.f ? v : 0.f);
          } else {  // EPI == 5
            const size_t cidx = (size_t)b * 2048 + col;
            out1[oidx] = (_Float16)(__expf(v - bias[cidx]) * resid[cidx]);
          }
        }
  }
}

// ---- fp32 -> fp16 convert, 8 elems/thread ----
__global__ __launch_bounds__(256) void convert_f32_f16(const float* __restrict__ in,
                                                       _Float16* __restrict__ out, long n8) {
  long i = (long)blockIdx.x * blockDim.x + threadIdx.x;
  if (i >= n8) return;
  f32x4 v0 = *(const f32x4*)(in + i * 8);
  f32x4 v1 = *(const f32x4*)(in + i * 8 + 4);
  f16x8 o;
  o[0] = (_Float16)v0[0]; o[1] = (_Float16)v0[1]; o[2] = (_Float16)v0[2]; o[3] = (_Float16)v0[3];
  o[4] = (_Float16)v1[0]; o[5] = (_Float16)v1[1]; o[6] = (_Float16)v1[2]; o[7] = (_Float16)v1[3];
  *(f16x8*)(out + i * 8) = o;
}

// ---- combine 16 row-chunk partials per column -> m_final, 1/Z ----
__global__ __launch_bounds__(256) void col_final(const float* __restrict__ pm,
                                                 const float* __restrict__ pZ,
                                                 float* __restrict__ mfin,
                                                 float* __restrict__ rZ) {
  const int b = blockIdx.z;
  const int c = blockIdx.x * 256 + threadIdx.x;
  float m = -3.4e38f;
  for (int k = 0; k < 16; ++k) m = fmaxf(m, pm[((size_t)b * 16 + k) * 2048 + c]);
  float Z = 0.f;
  for (int k = 0; k < 16; ++k) {
    const size_t idx = ((size_t)b * 16 + k) * 2048 + c;
    Z += pZ[idx] * __expf(pm[idx] - m);
  }
  mfin[(size_t)b * 2048 + c] = m;
  rZ[(size_t)b * 2048 + c]   = 1.f / Z;
}

// ---- x[b][j][c] (f32) -> xT[b][c][j] (f16), 32x32 LDS tile ----
__global__ void transpose_f32_to_f16(const float* __restrict__ x, _Float16* __restrict__ xT) {
  __shared__ float tile[32][33];
  const int b = blockIdx.z;
  const int c0 = blockIdx.x * 32, j0 = blockIdx.y * 32;
  const float* xb  = x  + (size_t)b * 2048 * 768;
  _Float16*    xTb = xT + (size_t)b * 768 * 2048;
  const int tx = threadIdx.x, ty = threadIdx.y;
#pragma unroll
  for (int dy = 0; dy < 32; dy += 8)
    tile[ty + dy][tx] = xb[(size_t)(j0 + ty + dy) * 768 + c0 + tx];
  __syncthreads();
#pragma unroll
  for (int dy = 0; dy < 32; dy += 8)
    xTb[(size_t)(c0 + ty + dy) * 2048 + j0 + tx] = (_Float16)tile[tx][ty + dy];
}

extern "C" void kernel_launch(void* const* d_in, const int* in_sizes, int n_in,
                              void* d_out, int out_size, void* d_ws, size_t ws_size,
                              hipStream_t stream) {
  const float* x  = (const float*)d_in[0];
  const float* Wk = (const float*)d_in[1];
  const float* bk = (const float*)d_in[2];
  const float* Wq = (const float*)d_in[3];
  const float* bq = (const float*)d_in[4];
  const float* W1 = (const float*)d_in[5];
  const float* W2 = (const float*)d_in[6];
  float* out = (float*)d_out;

  // ---- ws layout (~191 MiB peak) ----
  char* ws = (char*)d_ws;
  size_t off = 0;
  auto alloc = [&](size_t bytes) -> char* {
    char* p = ws + off;
    off += (bytes + 255) & ~(size_t)255;
    return p;
  };
  _Float16* xf = (_Float16*)alloc(25165824);   // x_f16; reused as xT
  _Float16* kf = (_Float16*)alloc(25165824);   // k;     reused as p_f16
  _Float16* qf = (_Float16*)alloc(25165824);   // q;     reused as h_f16
  _Float16* Wf = (_Float16*)alloc(4718592);    // Wk,Wq,W1,W2 f16
  _Float16* P  = (_Float16*)alloc(67108864);   // attn f16
  float*    pf32 = (float*)alloc(50331648);    // p f32 (residual for final)
  float*    pm = (float*)alloc(1048576);       // [8][16][2048] partial max
  float*    pZ = (float*)alloc(1048576);       // [8][16][2048] partial sumexp
  float*    mfin = (float*)alloc(65536);
  float*    rZ   = (float*)alloc(65536);

  _Float16* Wkf = Wf;
  _Float16* Wqf = Wf + 589824;
  _Float16* W1f = Wf + 2 * 589824;
  _Float16* W2f = Wf + 3 * 589824;
  _Float16* xT   = xf;  // alias: valid after proj GEMMs consumed x_f16
  _Float16* pf16 = kf;  // alias: valid after P pass consumed k
  _Float16* hf16 = qf;  // alias: valid after P pass consumed q

  const size_t sKV = (size_t)2048 * 768;
  const size_t sS  = (size_t)2048 * 2048;

  // 1. converts
  convert_f32_f16<<<6144, 256, 0, stream>>>(x,  xf,  1572864);
  convert_f32_f16<<<288,  256, 0, stream>>>(Wk, Wkf, 73728);
  convert_f32_f16<<<288,  256, 0, stream>>>(Wq, Wqf, 73728);
  convert_f32_f16<<<288,  256, 0, stream>>>(W1, W1f, 73728);
  convert_f32_f16<<<288,  256, 0, stream>>>(W2, W2f, 73728);

  // 2. projections: k, q  (M=16384, N=768, K=768)
  dim3 gProj(3, 64, 1);
  gemm256<0><<<gProj, 512, 0, stream>>>(xf, 0, 768, Wkf, 0, 768,
                                        nullptr, kf, nullptr, 0, 768, bk, nullptr, 768);
  gemm256<0><<<gProj, 512, 0, stream>>>(xf, 0, 768, Wqf, 0, 768,
                                        nullptr, qf, nullptr, 0, 768, bq, nullptr, 768);

  // 3. xT (overwrites x_f16 — proj GEMMs already done)
  transpose_f32_to_f16<<<dim3(24, 64, 8), dim3(32, 8), 0, stream>>>(x, xT);

  // 4. stats pass: S[b] = k_b * q_b^T, per-column (m, Z) partials only
  dim3 gS(8, 8, 8);
  gemm256<4><<<gS, 512, 0, stream>>>(kf, sKV, 768, qf, sKV, 768,
                                     pm, nullptr, pZ, 0, 0, nullptr, nullptr, 768);
  col_final<<<dim3(8, 1, 8), 256, 0, stream>>>(pm, pZ, mfin, rZ);

  // 5. P pass: recompute S, write P = exp(S - m_col) * rZ_col (f16)
  gemm256<5><<<gS, 512, 0, stream>>>(kf, sKV, 768, qf, sKV, 768,
                                     nullptr, P, nullptr, sS, 2048, mfin, rZ, 768);

  // 6. PV: p = x + P_b * x_b  (M=2048, N=768, K=2048), dual f32/f16 out
  dim3 gPV(3, 8, 8);
  gemm256<2><<<gPV, 512, 0, stream>>>(P, sS, 2048, xT, sKV, 2048,
                                      pf32, pf16, nullptr, sKV, 768,
                                      nullptr, x, 2048);

  // 7. FFN1: h = p * W1^T (f16 out)
  gemm256<0><<<gProj, 512, 0, stream>>>(pf16, 0, 768, W1f, 0, 768,
                                        nullptr, hf16, nullptr, 0, 768, nullptr, nullptr, 768);

  // 8. FFN2 + residual + relu: out = p + relu(h * W2^T)
  gemm256<3><<<gProj, 512, 0, stream>>>(hf16, 0, 768, W2f, 0, 768,
                                        out, nullptr, nullptr, 0, 768, nullptr, pf32, 768);
}

// Round 4
// 361.856 us; speedup vs baseline: 1.3687x; 1.0663x over previous
//
#include <hip/hip_runtime.h>

typedef float    f32x4 __attribute__((ext_vector_type(4)));
typedef _Float16 f16x8 __attribute__((ext_vector_type(8)));

// async global->LDS, 16B per lane (dest = wave-uniform base + lane*16)
__device__ __forceinline__ void gload16(const void* g, void* l) {
  __builtin_amdgcn_global_load_lds(
      (__attribute__((address_space(1))) void*)(const void*)g,
      (__attribute__((address_space(3))) void*)l,
      16, 0, 0);
}

// ================== 128x256 BT-GEMM engine, 2 blocks/CU ==================
// D = A(MxK) * B(NxK)^T, f16 in, f32 acc. 512 threads = 8 waves (2M x 4N),
// per-wave 64x64 output = acc[4][4]. BK=32, 3 LDS buffers (72KB -> 2
// blocks/CU), stage 2 tiles ahead, ONE barrier + counted vmcnt(3) per
// K-tile (never drains mid-loop). LDS XOR swizzle (slot^=(row>>1)&3)
// applied on global source + ds_read; linear gload_lds dest.
// EPI 0: out1(f16) = acc (+ bias[col])                      [kq proj, FFN1]
// EPI 2: pv = acc + resid; out0(f32)=pv; out1(f16)=pv       [PV residual]
// EPI 3: out0(f32) = resid + relu(acc)                      [final]
// EPI 4: per-column (m,Z) partials -> out0, out2 (32 chunks of 64 rows)
// EPI 5: out1(f16) = exp(acc - bias[b*2048+col]) * resid[b*2048+col]  [P]
template <int EPI>
__global__ __launch_bounds__(512, 4) void gemm_kt(
    const _Float16* __restrict__ A, size_t sA, int lda,
    const _Float16* __restrict__ B, size_t sB, int ldb,
    float* __restrict__ out0, _Float16* __restrict__ out1,
    float* __restrict__ out2,
    size_t sO, int ldo,
    const float* __restrict__ bias,
    const float* __restrict__ resid,
    int K) {
  __shared__ _Float16 lds[3 * 12288];  // per buf: A[128][32] (4096) + B[256][32] (8192)

  // XCD-bijective swizzle (all grids are multiples of 8 blocks)
  const int gx = gridDim.x, gy = gridDim.y;
  const int nblk = gx * gy * gridDim.z;
  int lin = (blockIdx.z * gy + blockIdx.y) * gx + blockIdx.x;
  lin = (lin & 7) * (nblk >> 3) + (lin >> 3);
  const int b  = lin / (gx * gy);
  const int r2 = lin - b * gx * gy;
  const int m0 = (r2 / gx) * 128;
  const int n0 = (r2 - (r2 / gx) * gx) * 256;

  const int t = threadIdx.x, lane = t & 63, w = t >> 6;
  const int wr = w >> 2;          // wave M-half: rows m0+wr*64..+63
  const int wc = w & 3;           // wave N-quarter: cols n0+wc*64..+63
  const int lr = lane & 15, lq = lane >> 4;

  const _Float16* Ab = A + (size_t)b * sA;
  const _Float16* Bb = B + (size_t)b * sB;

  // staging: thread t stages A seg t, B segs t and t+512 (16B each, 3 loads)
  const int arow = t >> 2;
  const int acol = ((t & 3) ^ ((arow >> 1) & 3)) * 8;  // pre-swizzled source col
  const _Float16* a_src  = Ab + (size_t)(m0 + arow) * lda + acol;
  const _Float16* b_src0 = Bb + (size_t)(n0 + arow) * ldb + acol;
  const _Float16* b_src1 = b_src0 + (size_t)128 * ldb;  // rows 128..255 (same swizzle: +128 rows keeps (row>>1)&3)
  const int a_dst  = t * 8;
  const int b_dst0 = 4096 + t * 8;
  const int b_dst1 = 4096 + (t + 512) * 8;

  // ds_read bases (swizzled)
  const int swz  = ((lr >> 1) & 3) << 3;
  const int a_rd = (wr * 64 + lr) * 32 + ((lq * 8) ^ swz);          // + f*512
  const int b_rd = 4096 + (wc * 64 + lr) * 32 + ((lq * 8) ^ swz);   // + j*512

  f32x4 acc[4][4];
#pragma unroll
  for (int f = 0; f < 4; ++f)
#pragma unroll
    for (int j = 0; j < 4; ++j) acc[f][j] = (f32x4){0.f, 0.f, 0.f, 0.f};

  const int NT = K >> 5;

  // prologue: stage tiles 0 and 1
  gload16(a_src,       lds + a_dst);
  gload16(b_src0,      lds + b_dst0);
  gload16(b_src1,      lds + b_dst1);
  gload16(a_src  + 32, lds + 12288 + a_dst);
  gload16(b_src0 + 32, lds + 12288 + b_dst0);
  gload16(b_src1 + 32, lds + 12288 + b_dst1);

  int buf = 0;
  for (int kt = 0; kt < NT; ++kt) {
    // counted wait: tile kt's 3 loads are oldest; leave tile kt+1's 3 in flight
    if (kt + 1 < NT) asm volatile("s_waitcnt vmcnt(3)" ::: "memory");
    else             asm volatile("s_waitcnt vmcnt(0)" ::: "memory");
    __builtin_amdgcn_s_barrier();
    __builtin_amdgcn_sched_barrier(0);  // no ds_read hoists above the barrier

    const _Float16* lb = lds + buf * 12288;
    const int nb = (buf + 2 >= 3) ? buf - 1 : buf + 2;
    _Float16* ln = lds + nb * 12288;

    f16x8 af[4], bf[4];
#pragma unroll
    for (int f = 0; f < 4; ++f) af[f] = *(const f16x8*)(lb + a_rd + f * 512);
#pragma unroll
    for (int j = 0; j < 4; ++j) bf[j] = *(const f16x8*)(lb + b_rd + j * 512);
    if (kt + 2 < NT) {  // stage tile kt+2 (buffer nb was last read in iter kt-1)
      const int ko = (kt + 2) * 32;
      gload16(a_src  + ko, ln + a_dst);
      gload16(b_src0 + ko, ln + b_dst0);
      gload16(b_src1 + ko, ln + b_dst1);
    }
    __builtin_amdgcn_s_setprio(1);
#pragma unroll
    for (int f = 0; f < 4; ++f)
#pragma unroll
      for (int j = 0; j < 4; ++j)
        acc[f][j] = __builtin_amdgcn_mfma_f32_16x16x32_f16(af[f], bf[j], acc[f][j], 0, 0, 0);
    __builtin_amdgcn_s_setprio(0);
    __builtin_amdgcn_sched_barrier(0);  // nothing (MFMA/lgkm) sinks into next tile
    buf = (buf + 1 >= 3) ? 0 : buf + 1;
  }

  // ---- epilogues. D frag: col = lr, row = lq*4 + r ----
  if constexpr (EPI == 4) {
#pragma unroll
    for (int j = 0; j < 4; ++j) {
      float m = -3.4e38f;
#pragma unroll
      for (int f = 0; f < 4; ++f)
#pragma unroll
        for (int r = 0; r < 4; ++r) m = fmaxf(m, acc[f][j][r]);
      float Z = 0.f;
#pragma unroll
      for (int f = 0; f < 4; ++f)
#pragma unroll
        for (int r = 0; r < 4; ++r) Z += __expf(acc[f][j][r] - m);
#pragma unroll
      for (int d = 16; d <= 32; d <<= 1) {  // combine 4 lq lanes per column
        float mo = __shfl_xor(m, d, 64);
        float Zo = __shfl_xor(Z, d, 64);
        float mn = fmaxf(m, mo);
        Z = Z * __expf(m - mn) + Zo * __expf(mo - mn);
        m = mn;
      }
      if (lq == 0) {
        const int chunk = (m0 >> 6) + wr;  // 32 chunks of 64 rows per batch
        const int col = n0 + wc * 64 + j * 16 + lr;
        const size_t sidx = ((size_t)b * 32 + chunk) * 2048 + col;
        out0[sidx] = m;
        out2[sidx] = Z;
      }
    }
  } else {
#pragma unroll
    for (int f = 0; f < 4; ++f)
#pragma unroll
      for (int j = 0; j < 4; ++j)
#pragma unroll
        for (int r = 0; r < 4; ++r) {
          const int row = m0 + wr * 64 + f * 16 + lq * 4 + r;
          const int col = n0 + wc * 64 + j * 16 + lr;
          const size_t oidx = (size_t)b * sO + (size_t)row * ldo + col;
          float v = acc[f][j][r];
          if constexpr (EPI == 0) {
            if (bias) v += bias[col];
            out1[oidx] = (_Float16)v;
          } else if constexpr (EPI == 2) {
            const float pv = v + resid[oidx];
            out0[oidx] = pv;
            out1[oidx] = (_Float16)pv;
          } else if constexpr (EPI == 3) {
            out0[oidx] = resid[oidx] + (v > 0.f ? v : 0.f);
          } else {  // EPI == 5
            const size_t cidx = (size_t)b * 2048 + col;
            out1[oidx] = (_Float16)(__expf(v - bias[cidx]) * resid[cidx]);
          }
        }
  }
}

// ---- fp32 -> fp16 convert, 8 elems/thread ----
__global__ __launch_bounds__(256) void convert_f32_f16(const float* __restrict__ in,
                                                       _Float16* __restrict__ out, long n8) {
  long i = (long)blockIdx.x * blockDim.x + threadIdx.x;
  if (i >= n8) return;
  f32x4 v0 = *(const f32x4*)(in + i * 8);
  f32x4 v1 = *(const f32x4*)(in + i * 8 + 4);
  f16x8 o;
  o[0] = (_Float16)v0[0]; o[1] = (_Float16)v0[1]; o[2] = (_Float16)v0[2]; o[3] = (_Float16)v0[3];
  o[4] = (_Float16)v1[0]; o[5] = (_Float16)v1[1]; o[6] = (_Float16)v1[2]; o[7] = (_Float16)v1[3];
  *(f16x8*)(out + i * 8) = o;
}

// ---- concat bk,bq -> bkq[1536] ----
__global__ void concat_bias(const float* __restrict__ bk, const float* __restrict__ bq,
                            float* __restrict__ bkq) {
  const int i = blockIdx.x * 256 + threadIdx.x;
  if (i < 768) bkq[i] = bk[i];
  else if (i < 1536) bkq[i] = bq[i - 768];
}

// ---- combine 32 row-chunk partials per column -> m_final, 1/Z ----
__global__ __launch_bounds__(256) void col_final(const float* __restrict__ pm,
                                                 const float* __restrict__ pZ,
                                                 float* __restrict__ mfin,
                                                 float* __restrict__ rZ) {
  const int b = blockIdx.z;
  const int c = blockIdx.x * 256 + threadIdx.x;
  float m = -3.4e38f;
  for (int k = 0; k < 32; ++k) m = fmaxf(m, pm[((size_t)b * 32 + k) * 2048 + c]);
  float Z = 0.f;
  for (int k = 0; k < 32; ++k) {
    const size_t idx = ((size_t)b * 32 + k) * 2048 + c;
    Z += pZ[idx] * __expf(pm[idx] - m);
  }
  mfin[(size_t)b * 2048 + c] = m;
  rZ[(size_t)b * 2048 + c]   = 1.f / Z;
}

// ---- x[b][j][c] (f32) -> xT[b][c][j] (f16), 32x32 LDS tile ----
__global__ void transpose_f32_to_f16(const float* __restrict__ x, _Float16* __restrict__ xT) {
  __shared__ float tile[32][33];
  const int b = blockIdx.z;
  const int c0 = blockIdx.x * 32, j0 = blockIdx.y * 32;
  const float* xb  = x  + (size_t)b * 2048 * 768;
  _Float16*    xTb = xT + (size_t)b * 768 * 2048;
  const int tx = threadIdx.x, ty = threadIdx.y;
#pragma unroll
  for (int dy = 0; dy < 32; dy += 8)
    tile[ty + dy][tx] = xb[(size_t)(j0 + ty + dy) * 768 + c0 + tx];
  __syncthreads();
#pragma unroll
  for (int dy = 0; dy < 32; dy += 8)
    xTb[(size_t)(c0 + ty + dy) * 2048 + j0 + tx] = (_Float16)tile[tx][ty + dy];
}

extern "C" void kernel_launch(void* const* d_in, const int* in_sizes, int n_in,
                              void* d_out, int out_size, void* d_ws, size_t ws_size,
                              hipStream_t stream) {
  const float* x  = (const float*)d_in[0];
  const float* Wk = (const float*)d_in[1];
  const float* bk = (const float*)d_in[2];
  const float* Wq = (const float*)d_in[3];
  const float* bq = (const float*)d_in[4];
  const float* W1 = (const float*)d_in[5];
  const float* W2 = (const float*)d_in[6];
  float* out = (float*)d_out;

  // ---- ws layout (~193 MiB peak) ----
  char* ws = (char*)d_ws;
  size_t off = 0;
  auto alloc = [&](size_t bytes) -> char* {
    char* p = ws + off;
    off += (bytes + 255) & ~(size_t)255;
    return p;
  };
  _Float16* xf = (_Float16*)alloc(25165824);   // x_f16; reused as xT
  _Float16* kq = (_Float16*)alloc(50331648);   // [16384][1536] k|q; reused as p_f16 + h_f16
  _Float16* Wf = (_Float16*)alloc(4718592);    // Wkq (1536x768), W1, W2 f16
  _Float16* P  = (_Float16*)alloc(67108864);   // attn f16
  float*    pf32 = (float*)alloc(50331648);    // p f32 (residual for final)
  float*    pm = (float*)alloc(2097152);       // [8][32][2048] partial max
  float*    pZ = (float*)alloc(2097152);       // [8][32][2048] partial sumexp
  float*    mfin = (float*)alloc(65536);
  float*    rZ   = (float*)alloc(65536);
  float*    bkq  = (float*)alloc(6144);

  _Float16* Wkqf = Wf;                          // rows 0..767 = Wk, 768..1535 = Wq
  _Float16* W1f  = Wf + 2 * 589824;
  _Float16* W2f  = Wf + 3 * 589824;
  _Float16* xT   = xf;                          // alias after proj consumed x_f16
  _Float16* pf16 = kq;                          // alias after P pass consumed kq
  _Float16* hf16 = kq + 12582912;               // second 24MB half of kq block

  const size_t sKQ = (size_t)2048 * 1536;
  const size_t sS  = (size_t)2048 * 2048;
  const size_t sKV = (size_t)2048 * 768;

  // 1. converts
  convert_f32_f16<<<6144, 256, 0, stream>>>(x,  xf, 1572864);
  convert_f32_f16<<<288,  256, 0, stream>>>(Wk, Wkqf, 73728);
  convert_f32_f16<<<288,  256, 0, stream>>>(Wq, Wkqf + 589824, 73728);
  convert_f32_f16<<<288,  256, 0, stream>>>(W1, W1f, 73728);
  convert_f32_f16<<<288,  256, 0, stream>>>(W2, W2f, 73728);
  concat_bias<<<6, 256, 0, stream>>>(bk, bq, bkq);

  // 2. merged projection: kq = x * Wkq^T + bkq  (M=16384, N=1536, K=768)
  gemm_kt<0><<<dim3(6, 128, 1), 512, 0, stream>>>(xf, 0, 768, Wkqf, 0, 768,
                                                  nullptr, kq, nullptr, 0, 1536,
                                                  bkq, nullptr, 768);

  // 3. xT (overwrites x_f16 — proj done)
  transpose_f32_to_f16<<<dim3(24, 64, 8), dim3(32, 8), 0, stream>>>(x, xT);

  // 4. stats pass: S[b] = k_b * q_b^T, per-column (m, Z) partials
  dim3 gS(8, 16, 8);
  gemm_kt<4><<<gS, 512, 0, stream>>>(kq, sKQ, 1536, kq + 768, sKQ, 1536,
                                     pm, nullptr, pZ, 0, 0, nullptr, nullptr, 768);
  col_final<<<dim3(8, 1, 8), 256, 0, stream>>>(pm, pZ, mfin, rZ);

  // 5. P pass: recompute S, write P = exp(S - m_col) * rZ_col (f16)
  gemm_kt<5><<<gS, 512, 0, stream>>>(kq, sKQ, 1536, kq + 768, sKQ, 1536,
                                     nullptr, P, nullptr, sS, 2048, mfin, rZ, 768);

  // 6. PV: p = x + P_b * x_b  (M=2048, N=768, K=2048), dual f32/f16 out
  gemm_kt<2><<<dim3(3, 16, 8), 512, 0, stream>>>(P, sS, 2048, xT, sKV, 2048,
                                                 pf32, pf16, nullptr, sKV, 768,
                                                 nullptr, x, 2048);

  // 7. FFN1: h = p * W1^T (f16 out)
  gemm_kt<0><<<dim3(3, 128, 1), 512, 0, stream>>>(pf16, 0, 768, W1f, 0, 768,
                                                  nullptr, hf16, nullptr, 0, 768,
                                                  nullptr, nullptr, 768);

  // 8. FFN2 + residual + relu: out = p + relu(h * W2^T)
  gemm_kt<3><<<dim3(3, 128, 1), 512, 0, stream>>>(hf16, 0, 768, W2f, 0, 768,
                                                  out, nullptr, nullptr, 0, 768,
                                                  nullptr, pf32, 768);
}

// Round 7
// 306.032 us; speedup vs baseline: 1.6184x; 1.1824x over previous
//
#include <hip/hip_runtime.h>

typedef float    f32x4 __attribute__((ext_vector_type(4)));
typedef _Float16 f16x8 __attribute__((ext_vector_type(8)));

// async global->LDS, 16B per lane (dest = wave-uniform base + lane*16)
__device__ __forceinline__ void gload16(const void* g, void* l) {
  __builtin_amdgcn_global_load_lds(
      (__attribute__((address_space(1))) void*)(const void*)g,
      (__attribute__((address_space(3))) void*)l,
      16, 0, 0);
}

// ================== 128x256 BT-GEMM engine ==================
// D = A(MxK) * B(NxK)^T, f16 in, f32 acc. 512 threads = 8 waves (2M x 4N),
// per-wave 64x64 = acc[4][4]. BK=32, 3 LDS bufs (72KB static), stage 2
// ahead, one barrier + counted vmcnt(3)/K-tile. XOR swizzle source+read.
// EPI 0: out1(f16) = acc + bias[col]                        [kq proj, FFN1]
// EPI 3: out0(f32) = resid + relu(acc)                      [final]
// EPI 4: E' = exp(acc - m_chunk) -> out1(f16); (m,Z) partials -> out0,out2
// EPI 6: fused PV: A-frag *= c-vec (LDS c-table); pv=acc+resid dual-write
template <int EPI>
__global__ __launch_bounds__(512, 4) void gemm_kt(
    const _Float16* __restrict__ A, size_t sA, int lda,
    const _Float16* __restrict__ B, size_t sB, int ldb,
    float* __restrict__ out0, _Float16* __restrict__ out1,
    float* __restrict__ out2,
    size_t sO, int ldo,
    const float* __restrict__ bias,
    const float* __restrict__ resid,
    const _Float16* __restrict__ cf,
    int K) {
  __shared__ _Float16 lds[3 * 12288];              // 73728 B (3 bufs)
  __shared__ _Float16 clds[(EPI == 6) ? 4096 : 1]; // EPI6: [2 chunks][2048]

  // XCD-bijective swizzle (all grids are multiples of 8 blocks)
  const int gx = gridDim.x, gy = gridDim.y;
  const int nblk = gx * gy * gridDim.z;
  int lin = (blockIdx.z * gy + blockIdx.y) * gx + blockIdx.x;
  lin = (lin & 7) * (nblk >> 3) + (lin >> 3);
  const int b  = lin / (gx * gy);
  const int r2 = lin - b * gx * gy;
  const int m0 = (r2 / gx) * 128;
  const int n0 = (r2 - (r2 / gx) * gx) * 256;

  const int t = threadIdx.x, lane = t & 63, w = t >> 6;
  const int wr = w >> 2;          // wave M-half: rows m0+wr*64..+63
  const int wc = w & 3;           // wave N-quarter: cols n0+wc*64..+63
  const int lr = lane & 15, lq = lane >> 4;

  const _Float16* Ab = A + (size_t)b * sA;
  const _Float16* Bb = B + (size_t)b * sB;

  // staging: thread t stages A seg t, B segs t and t+512 (16B each)
  const int arow = t >> 2;
  const int acol = ((t & 3) ^ ((arow >> 1) & 3)) * 8;  // pre-swizzled source col
  const _Float16* a_src  = Ab + (size_t)(m0 + arow) * lda + acol;
  const _Float16* b_src0 = Bb + (size_t)(n0 + arow) * ldb + acol;
  const _Float16* b_src1 = b_src0 + (size_t)128 * ldb;  // +128 rows: same swizzle class
  const int a_dst  = t * 8;
  const int b_dst0 = 4096 + t * 8;
  const int b_dst1 = 4096 + (t + 512) * 8;

  // ds_read bases (swizzled)
  const int swz  = ((lr >> 1) & 3) << 3;
  const int koff = (lq * 8) ^ swz;                       // swizzled k slot in LDS
  const int a_rd = (wr * 64 + lr) * 32 + koff;           // + f*512
  const int b_rd = 4096 + (wc * 64 + lr) * 32 + koff;    // + j*512

  f32x4 acc[4][4];
#pragma unroll
  for (int f = 0; f < 4; ++f)
#pragma unroll
    for (int j = 0; j < 4; ++j) acc[f][j] = (f32x4){0.f, 0.f, 0.f, 0.f};

  const int NT = K >> 5;

  // prologue: (EPI6) c-table, then stage tiles 0 and 1
  if constexpr (EPI == 6)
    gload16(cf + ((size_t)b * 32 + (m0 >> 6)) * 2048 + t * 8, clds + t * 8);
  gload16(a_src,       lds + a_dst);
  gload16(b_src0,      lds + b_dst0);
  gload16(b_src1,      lds + b_dst1);
  gload16(a_src  + 32, lds + 12288 + a_dst);
  gload16(b_src0 + 32, lds + 12288 + b_dst0);
  gload16(b_src1 + 32, lds + 12288 + b_dst1);

  int buf = 0;
  for (int kt = 0; kt < NT; ++kt) {
    // counted wait: tile kt's loads (and, at kt=0, the c-load) are oldest;
    // leave tile kt+1's 3 in flight
    if (kt + 1 < NT) asm volatile("s_waitcnt vmcnt(3)" ::: "memory");
    else             asm volatile("s_waitcnt vmcnt(0)" ::: "memory");
    __builtin_amdgcn_s_barrier();
    __builtin_amdgcn_sched_barrier(0);  // no ds_read hoists above the barrier

    const _Float16* lb = lds + buf * 12288;
    const int nb = (buf + 2 >= 3) ? buf - 1 : buf + 2;
    _Float16* ln = lds + nb * 12288;

    f16x8 af[4], bf[4], cv;
    if constexpr (EPI == 6)
      // c-table is linear in clds; fragment's global k-group is lq (the
      // store/read XOR cancels) -> index by lq*8, NOT koff
      cv = *(const f16x8*)(clds + wr * 2048 + kt * 32 + lq * 8);
#pragma unroll
    for (int f = 0; f < 4; ++f) {
      af[f] = *(const f16x8*)(lb + a_rd + f * 512);
      if constexpr (EPI == 6) af[f] = af[f] * cv;
    }
#pragma unroll
    for (int j = 0; j < 4; ++j) bf[j] = *(const f16x8*)(lb + b_rd + j * 512);
    if (kt + 2 < NT) {
      const int ko = (kt + 2) * 32;
      gload16(a_src  + ko, ln + a_dst);
      gload16(b_src0 + ko, ln + b_dst0);
      gload16(b_src1 + ko, ln + b_dst1);
    }
    __builtin_amdgcn_s_setprio(1);
#pragma unroll
    for (int f = 0; f < 4; ++f)
#pragma unroll
      for (int j = 0; j < 4; ++j)
        acc[f][j] = __builtin_amdgcn_mfma_f32_16x16x32_f16(af[f], bf[j], acc[f][j], 0, 0, 0);
    __builtin_amdgcn_s_setprio(0);
    __builtin_amdgcn_sched_barrier(0);  // nothing sinks into next tile
    buf = (buf + 1 >= 3) ? 0 : buf + 1;
  }

  // ---- epilogues. D frag: col = lr, row = lq*4 + r ----
  if constexpr (EPI == 4) {
#pragma unroll
    for (int j = 0; j < 4; ++j) {
      float m = -3.4e38f;
#pragma unroll
      for (int f = 0; f < 4; ++f)
#pragma unroll
        for (int r = 0; r < 4; ++r) m = fmaxf(m, acc[f][j][r]);
#pragma unroll
      for (int d = 16; d <= 32; d <<= 1) m = fmaxf(m, __shfl_xor(m, d, 64));
      // E' = exp(acc - m_chunk), store f16; Z from rounded values
      float Z = 0.f;
      const int col = n0 + wc * 64 + j * 16 + lr;
#pragma unroll
      for (int f = 0; f < 4; ++f)
#pragma unroll
        for (int r = 0; r < 4; ++r) {
          const _Float16 eh = (_Float16)__expf(acc[f][j][r] - m);
          const int row = m0 + wr * 64 + f * 16 + lq * 4 + r;
          out1[(size_t)b * sO + (size_t)row * ldo + col] = eh;
          Z += (float)eh;
        }
#pragma unroll
      for (int d = 16; d <= 32; d <<= 1) Z += __shfl_xor(Z, d, 64);
      if (lq == 0) {
        const int chunk = (m0 >> 6) + wr;  // 32 chunks of 64 rows per batch
        const size_t sidx = ((size_t)b * 32 + chunk) * 2048 + col;
        out0[sidx] = m;
        out2[sidx] = Z;
      }
    }
  } else {
#pragma unroll
    for (int f = 0; f < 4; ++f)
#pragma unroll
      for (int j = 0; j < 4; ++j)
#pragma unroll
        for (int r = 0; r < 4; ++r) {
          const int row = m0 + wr * 64 + f * 16 + lq * 4 + r;
          const int col = n0 + wc * 64 + j * 16 + lr;
          const size_t oidx = (size_t)b * sO + (size_t)row * ldo + col;
          float v = acc[f][j][r];
          if constexpr (EPI == 0) {
            if (bias) v += bias[col];
            out1[oidx] = (_Float16)v;
          } else if constexpr (EPI == 6) {
            const float pv = v + resid[oidx];
            out0[oidx] = pv;
            out1[oidx] = (_Float16)pv;
          } else {  // EPI == 3
            out0[oidx] = resid[oidx] + (v > 0.f ? v : 0.f);
          }
        }
  }
}

// ---- fp32 -> fp16 convert, 8 elems/thread ----
__global__ __launch_bounds__(256) void convert_f32_f16(const float* __restrict__ in,
                                                       _Float16* __restrict__ out, long n8) {
  long i = (long)blockIdx.x * blockDim.x + threadIdx.x;
  if (i >= n8) return;
  f32x4 v0 = *(const f32x4*)(in + i * 8);
  f32x4 v1 = *(const f32x4*)(in + i * 8 + 4);
  f16x8 o;
  o[0] = (_Float16)v0[0]; o[1] = (_Float16)v0[1]; o[2] = (_Float16)v0[2]; o[3] = (_Float16)v0[3];
  o[4] = (_Float16)v1[0]; o[5] = (_Float16)v1[1]; o[6] = (_Float16)v1[2]; o[7] = (_Float16)v1[3];
  *(f16x8*)(out + i * 8) = o;
}

// ---- concat bk,bq -> bkq[1536] ----
__global__ void concat_bias(const float* __restrict__ bk, const float* __restrict__ bq,
                            float* __restrict__ bkq) {
  const int i = blockIdx.x * 256 + threadIdx.x;
  if (i < 768) bkq[i] = bk[i];
  else if (i < 1536) bkq[i] = bq[i - 768];
}

// ---- combine 32 chunk partials per column -> c[b][chunk][col] (f16) ----
// c = exp(m_chunk - m) / Z
__global__ __launch_bounds__(256) void col_final(const float* __restrict__ pm,
                                                 const float* __restrict__ pZ,
                                                 _Float16* __restrict__ c) {
  const int b = blockIdx.z;
  const int col = blockIdx.x * 256 + threadIdx.x;
  float mv[32];
  float m = -3.4e38f;
#pragma unroll
  for (int k = 0; k < 32; ++k) {
    mv[k] = pm[((size_t)b * 32 + k) * 2048 + col];
    m = fmaxf(m, mv[k]);
  }
  float Z = 0.f;
#pragma unroll
  for (int k = 0; k < 32; ++k)
    Z += pZ[((size_t)b * 32 + k) * 2048 + col] * __expf(mv[k] - m);
  const float rZ = 1.f / Z;
#pragma unroll
  for (int k = 0; k < 32; ++k)
    c[((size_t)b * 32 + k) * 2048 + col] = (_Float16)(__expf(mv[k] - m) * rZ);
}

// ---- x[b][j][c] (f32) -> xT[b][c][j] (f16), 32x32 LDS tile ----
__global__ void transpose_f32_to_f16(const float* __restrict__ x, _Float16* __restrict__ xT) {
  __shared__ float tile[32][33];
  const int b = blockIdx.z;
  const int c0 = blockIdx.x * 32, j0 = blockIdx.y * 32;
  const float* xb  = x  + (size_t)b * 2048 * 768;
  _Float16*    xTb = xT + (size_t)b * 768 * 2048;
  const int tx = threadIdx.x, ty = threadIdx.y;
#pragma unroll
  for (int dy = 0; dy < 32; dy += 8)
    tile[ty + dy][tx] = xb[(size_t)(j0 + ty + dy) * 768 + c0 + tx];
  __syncthreads();
#pragma unroll
  for (int dy = 0; dy < 32; dy += 8)
    xTb[(size_t)(c0 + ty + dy) * 2048 + j0 + tx] = (_Float16)tile[tx][ty + dy];
}

extern "C" void kernel_launch(void* const* d_in, const int* in_sizes, int n_in,
                              void* d_out, int out_size, void* d_ws, size_t ws_size,
                              hipStream_t stream) {
  const float* x  = (const float*)d_in[0];
  const float* Wk = (const float*)d_in[1];
  const float* bk = (const float*)d_in[2];
  const float* Wq = (const float*)d_in[3];
  const float* bq = (const float*)d_in[4];
  const float* W1 = (const float*)d_in[5];
  const float* W2 = (const float*)d_in[6];
  float* out = (float*)d_out;

  // ---- ws layout (~193 MiB peak) ----
  char* ws = (char*)d_ws;
  size_t off = 0;
  auto alloc = [&](size_t bytes) -> char* {
    char* p = ws + off;
    off += (bytes + 255) & ~(size_t)255;
    return p;
  };
  _Float16* xf = (_Float16*)alloc(25165824);   // x_f16; reused as xT
  _Float16* kq = (_Float16*)alloc(50331648);   // [16384][1536] k|q; reused as p_f16+c+h_f16
  _Float16* Wf = (_Float16*)alloc(4718592);    // Wkq, W1, W2 f16
  _Float16* E  = (_Float16*)alloc(67108864);   // E' = exp(S - m_chunk) f16 [8][2048][2048]
  float*    pf32 = (float*)alloc(50331648);    // p f32 (residual for final)
  float*    pm = (float*)alloc(2097152);       // [8][32][2048] partial max
  float*    pZ = (float*)alloc(2097152);       // [8][32][2048] partial sumexp
  float*    bkq  = (float*)alloc(6144);

  _Float16* Wkqf = Wf;
  _Float16* W1f  = Wf + 2 * 589824;
  _Float16* W2f  = Wf + 3 * 589824;
  _Float16* xT   = xf;                 // alias after proj consumed x_f16
  _Float16* pf16 = kq;                 // alias after E pass consumed kq (first 24MiB)
  _Float16* cT   = kq + 12582912;      // c table (1MiB) in dead kq space
  _Float16* hf16 = kq + 12582912;      // FFN1 output overwrites cT after fused PV

  const size_t sKQ = (size_t)2048 * 1536;
  const size_t sS  = (size_t)2048 * 2048;
  const size_t sKV = (size_t)2048 * 768;

  // 1. converts
  convert_f32_f16<<<6144, 256, 0, stream>>>(x,  xf, 1572864);
  convert_f32_f16<<<288,  256, 0, stream>>>(Wk, Wkqf, 73728);
  convert_f32_f16<<<288,  256, 0, stream>>>(Wq, Wkqf + 589824, 73728);
  convert_f32_f16<<<288,  256, 0, stream>>>(W1, W1f, 73728);
  convert_f32_f16<<<288,  256, 0, stream>>>(W2, W2f, 73728);
  concat_bias<<<6, 256, 0, stream>>>(bk, bq, bkq);

  // 2. merged projection: kq = x * Wkq^T + bkq  (M=16384, N=1536, K=768)
  gemm_kt<0><<<dim3(6, 128, 1), 512, 0, stream>>>(xf, 0, 768, Wkqf, 0, 768,
                                                  nullptr, kq, nullptr, 0, 1536,
                                                  bkq, nullptr, nullptr, 768);

  // 3. xT (overwrites x_f16 — proj done)
  transpose_f32_to_f16<<<dim3(24, 64, 8), dim3(32, 8), 0, stream>>>(x, xT);

  // 4. E pass: S = k q^T; E' = exp(S - m_chunk) f16 + (m,Z) partials
  gemm_kt<4><<<dim3(8, 16, 8), 512, 0, stream>>>(kq, sKQ, 1536, kq + 768, sKQ, 1536,
                                                 pm, E, pZ, sS, 2048,
                                                 nullptr, nullptr, nullptr, 768);
  col_final<<<dim3(8, 1, 8), 256, 0, stream>>>(pm, pZ, cT);

  // 5. fused PV: p = x + (E' .* c) x  (M=2048, N=768, K=2048)
  gemm_kt<6><<<dim3(3, 16, 8), 512, 0, stream>>>(E, sS, 2048, xT, sKV, 2048,
                                                 pf32, pf16, nullptr, sKV, 768,
                                                 nullptr, x, cT, 2048);

  // 6. FFN1: h = p * W1^T (f16 out; overwrites cT — fused PV done)
  gemm_kt<0><<<dim3(3, 128, 1), 512, 0, stream>>>(pf16, 0, 768, W1f, 0, 768,
                                                  nullptr, hf16, nullptr, 0, 768,
                                                  nullptr, nullptr, nullptr, 768);

  // 7. FFN2 + residual + relu: out = p + relu(h * W2^T)
  gemm_kt<3><<<dim3(3, 128, 1), 512, 0, stream>>>(hf16, 0, 768, W2f, 0, 768,
                                                  out, nullptr, nullptr, 0, 768,
                                                  nullptr, pf32, nullptr, 768);
}

// Round 10
// 282.906 us; speedup vs baseline: 1.7507x; 1.0817x over previous
//
#include <hip/hip_runtime.h>

typedef float    f32x4 __attribute__((ext_vector_type(4)));
typedef _Float16 f16x8 __attribute__((ext_vector_type(8)));
typedef _Float16 f16x4 __attribute__((ext_vector_type(4)));

// async global->LDS, 16B per lane (dest = wave-uniform base + lane*16)
__device__ __forceinline__ void gload16(const void* g, void* l) {
  __builtin_amdgcn_global_load_lds(
      (__attribute__((address_space(1))) void*)(const void*)g,
      (__attribute__((address_space(3))) void*)l,
      16, 0, 0);
}

// ================== 128x256 BT-GEMM engine ==================
// D = A(MxK) * B(NxK)^T, f16 in, f32 acc. 512 threads = 8 waves (2M x 4N),
// per-wave 64x64 = acc[4][4]. BK=32, 3 LDS bufs (72KB static), stage 2
// ahead, one barrier + counted vmcnt per K-tile (EPI6: vmcnt(3) also covers
// the prologue c-load as 7th op; never drains mid-loop). XOR swizzle.
// EPI 0: out1(f16) = acc + bias[col]                        [kq proj, FFN1]
// EPI 3: out0(f32) = (f32)residh + relu(acc)                [final]
// EPI 4: E' = exp(acc - m_chunk) -> out1(f16); (m,Z) partials -> out0,out2
// EPI 6: fused PV: A-frag *= cv (LDS c-table); out1(f16) = acc + resid(f32)
template <int EPI>
__global__ __launch_bounds__(512, 4) void gemm_kt(
    const _Float16* __restrict__ A, size_t sA, int lda,
    const _Float16* __restrict__ B, size_t sB, int ldb,
    float* __restrict__ out0, _Float16* __restrict__ out1,
    float* __restrict__ out2,
    size_t sO, int ldo,
    const float* __restrict__ bias,
    const float* __restrict__ resid,
    const _Float16* __restrict__ residh,
    const _Float16* __restrict__ cf,
    int K) {
  __shared__ _Float16 lds[3 * 12288];              // 73728 B (3 bufs)
  __shared__ _Float16 clds[(EPI == 6) ? 4096 : 1]; // EPI6: [2 chunks][2048]

  // XCD-bijective swizzle (all grids are multiples of 8 blocks)
  const int gx = gridDim.x, gy = gridDim.y;
  const int nblk = gx * gy * gridDim.z;
  int lin = (blockIdx.z * gy + blockIdx.y) * gx + blockIdx.x;
  lin = (lin & 7) * (nblk >> 3) + (lin >> 3);
  const int b  = lin / (gx * gy);
  const int r2 = lin - b * gx * gy;
  const int m0 = (r2 / gx) * 128;
  const int n0 = (r2 - (r2 / gx) * gx) * 256;

  const int t = threadIdx.x, lane = t & 63, w = t >> 6;
  const int wr = w >> 2;          // wave M-half: rows m0+wr*64..+63
  const int wc = w & 3;           // wave N-quarter: cols n0+wc*64..+63
  const int lr = lane & 15, lq = lane >> 4;

  const _Float16* Ab = A + (size_t)b * sA;
  const _Float16* Bb = B + (size_t)b * sB;

  // staging: thread t stages A seg t, B segs t and t+512 (16B each)
  const int arow = t >> 2;
  const int acol = ((t & 3) ^ ((arow >> 1) & 3)) * 8;  // pre-swizzled source col
  const _Float16* a_src  = Ab + (size_t)(m0 + arow) * lda + acol;
  const _Float16* b_src0 = Bb + (size_t)(n0 + arow) * ldb + acol;
  const _Float16* b_src1 = b_src0 + (size_t)128 * ldb;  // +128 rows: same swizzle class
  const int a_dst  = t * 8;
  const int b_dst0 = 4096 + t * 8;
  const int b_dst1 = 4096 + (t + 512) * 8;

  // ds_read bases (swizzled)
  const int swz  = ((lr >> 1) & 3) << 3;
  const int koff = (lq * 8) ^ swz;                       // swizzled k slot in LDS
  const int a_rd = (wr * 64 + lr) * 32 + koff;           // + f*512
  const int b_rd = 4096 + (wc * 64 + lr) * 32 + koff;    // + j*512

  f32x4 acc[4][4];
#pragma unroll
  for (int f = 0; f < 4; ++f)
#pragma unroll
    for (int j = 0; j < 4; ++j) acc[f][j] = (f32x4){0.f, 0.f, 0.f, 0.f};

  const int NT = K >> 5;

  // prologue: (EPI6) c-table, then stage tiles 0 and 1
  if constexpr (EPI == 6)
    gload16(cf + ((size_t)b * 32 + (m0 >> 6)) * 2048 + t * 8, clds + t * 8);
  gload16(a_src,       lds + a_dst);
  gload16(b_src0,      lds + b_dst0);
  gload16(b_src1,      lds + b_dst1);
  gload16(a_src  + 32, lds + 12288 + a_dst);
  gload16(b_src0 + 32, lds + 12288 + b_dst0);
  gload16(b_src1 + 32, lds + 12288 + b_dst1);

  int buf = 0;
  for (int kt = 0; kt < NT; ++kt) {
    // counted wait: tile kt's loads (and, at kt=0, the c-load) are oldest;
    // leave tile kt+1's 3 in flight
    if (kt + 1 < NT) asm volatile("s_waitcnt vmcnt(3)" ::: "memory");
    else             asm volatile("s_waitcnt vmcnt(0)" ::: "memory");
    __builtin_amdgcn_s_barrier();
    __builtin_amdgcn_sched_barrier(0);  // no ds_read hoists above the barrier

    const _Float16* lb = lds + buf * 12288;
    const int nb = (buf + 2 >= 3) ? buf - 1 : buf + 2;
    _Float16* ln = lds + nb * 12288;

    f16x8 af[4], bf[4], cv;
    if constexpr (EPI == 6)
      // c-table is linear in clds; fragment's global k-group is lq (the
      // store/read XOR cancels) -> index by lq*8, NOT koff
      cv = *(const f16x8*)(clds + wr * 2048 + kt * 32 + lq * 8);
#pragma unroll
    for (int f = 0; f < 4; ++f) {
      af[f] = *(const f16x8*)(lb + a_rd + f * 512);
      if constexpr (EPI == 6) af[f] = af[f] * cv;
    }
#pragma unroll
    for (int j = 0; j < 4; ++j) bf[j] = *(const f16x8*)(lb + b_rd + j * 512);
    if (kt + 2 < NT) {
      const int ko = (kt + 2) * 32;
      gload16(a_src  + ko, ln + a_dst);
      gload16(b_src0 + ko, ln + b_dst0);
      gload16(b_src1 + ko, ln + b_dst1);
    }
    __builtin_amdgcn_s_setprio(1);
#pragma unroll
    for (int f = 0; f < 4; ++f)
#pragma unroll
      for (int j = 0; j < 4; ++j)
        acc[f][j] = __builtin_amdgcn_mfma_f32_16x16x32_f16(af[f], bf[j], acc[f][j], 0, 0, 0);
    __builtin_amdgcn_s_setprio(0);
    __builtin_amdgcn_sched_barrier(0);  // nothing sinks into next tile
    buf = (buf + 1 >= 3) ? 0 : buf + 1;
  }

  // ---- epilogues. D frag: col = lr, row = lq*4 + r ----
  if constexpr (EPI == 4) {
#pragma unroll
    for (int j = 0; j < 4; ++j) {
      float m = -3.4e38f;
#pragma unroll
      for (int f = 0; f < 4; ++f)
#pragma unroll
        for (int r = 0; r < 4; ++r) m = fmaxf(m, acc[f][j][r]);
#pragma unroll
      for (int d = 16; d <= 32; d <<= 1) m = fmaxf(m, __shfl_xor(m, d, 64));
      // E' = exp(acc - m_chunk), store f16; Z from rounded values
      float Z = 0.f;
      const int col = n0 + wc * 64 + j * 16 + lr;
#pragma unroll
      for (int f = 0; f < 4; ++f)
#pragma unroll
        for (int r = 0; r < 4; ++r) {
          const _Float16 eh = (_Float16)__expf(acc[f][j][r] - m);
          const int row = m0 + wr * 64 + f * 16 + lq * 4 + r;
          out1[(size_t)b * sO + (size_t)row * ldo + col] = eh;
          Z += (float)eh;
        }
#pragma unroll
      for (int d = 16; d <= 32; d <<= 1) Z += __shfl_xor(Z, d, 64);
      if (lq == 0) {
        const int chunk = (m0 >> 6) + wr;  // 32 chunks of 64 rows per batch
        const size_t sidx = ((size_t)b * 32 + chunk) * 2048 + col;
        out0[sidx] = m;
        out2[sidx] = Z;
      }
    }
  } else {
#pragma unroll
    for (int f = 0; f < 4; ++f)
#pragma unroll
      for (int j = 0; j < 4; ++j)
#pragma unroll
        for (int r = 0; r < 4; ++r) {
          const int row = m0 + wr * 64 + f * 16 + lq * 4 + r;
          const int col = n0 + wc * 64 + j * 16 + lr;
          const size_t oidx = (size_t)b * sO + (size_t)row * ldo + col;
          float v = acc[f][j][r];
          if constexpr (EPI == 0) {
            if (bias) v += bias[col];
            out1[oidx] = (_Float16)v;
          } else if constexpr (EPI == 6) {
            out1[oidx] = (_Float16)(v + resid[oidx]);  // p in f16 only
          } else {  // EPI == 3
            out0[oidx] = (float)residh[oidx] + (v > 0.f ? v : 0.f);
          }
        }
  }
}

// ---- fp32 -> fp16 convert, 8 elems/thread (weights) ----
__global__ __launch_bounds__(256) void convert_f32_f16(const float* __restrict__ in,
                                                       _Float16* __restrict__ out, long n8) {
  long i = (long)blockIdx.x * blockDim.x + threadIdx.x;
  if (i >= n8) return;
  f32x4 v0 = *(const f32x4*)(in + i * 8);
  f32x4 v1 = *(const f32x4*)(in + i * 8 + 4);
  f16x8 o;
  o[0] = (_Float16)v0[0]; o[1] = (_Float16)v0[1]; o[2] = (_Float16)v0[2]; o[3] = (_Float16)v0[3];
  o[4] = (_Float16)v1[0]; o[5] = (_Float16)v1[1]; o[6] = (_Float16)v1[2]; o[7] = (_Float16)v1[3];
  *(f16x8*)(out + i * 8) = o;
}

// ---- concat bk,bq -> bkq[1536] ----
__global__ void concat_bias(const float* __restrict__ bk, const float* __restrict__ bq,
                            float* __restrict__ bkq) {
  const int i = blockIdx.x * 256 + threadIdx.x;
  if (i < 768) bkq[i] = bk[i];
  else if (i < 1536) bkq[i] = bq[i - 768];
}

// ---- combine 32 chunk partials per column -> c[b][chunk][col] (f16) ----
// c = exp(m_chunk - m) / Z
__global__ __launch_bounds__(256) void col_final(const float* __restrict__ pm,
                                                 const float* __restrict__ pZ,
                                                 _Float16* __restrict__ c) {
  const int b = blockIdx.z;
  const int col = blockIdx.x * 256 + threadIdx.x;
  float mv[32];
  float m = -3.4e38f;
#pragma unroll
  for (int k = 0; k < 32; ++k) {
    mv[k] = pm[((size_t)b * 32 + k) * 2048 + col];
    m = fmaxf(m, mv[k]);
  }
  float Z = 0.f;
#pragma unroll
  for (int k = 0; k < 32; ++k)
    Z += pZ[((size_t)b * 32 + k) * 2048 + col] * __expf(mv[k] - m);
  const float rZ = 1.f / Z;
#pragma unroll
  for (int k = 0; k < 32; ++k)
    c[((size_t)b * 32 + k) * 2048 + col] = (_Float16)(__expf(mv[k] - m) * rZ);
}

// ---- x[b][j][c] f32 -> xf[b][j][c] f16 AND xT[b][c][j] f16, one pass ----
__global__ void xprep(const float* __restrict__ x, _Float16* __restrict__ xf,
                      _Float16* __restrict__ xT) {
  __shared__ float tile[32][33];
  const int b = blockIdx.z;
  const int c0 = blockIdx.x * 32, j0 = blockIdx.y * 32;
  const float* xb = x + (size_t)b * 2048 * 768;
  const int tx = threadIdx.x, ty = threadIdx.y;  // 32 x 8
#pragma unroll
  for (int dy = 0; dy < 32; dy += 8)
    tile[ty + dy][tx] = xb[(size_t)(j0 + ty + dy) * 768 + c0 + tx];
  __syncthreads();
  // straight f16 copy, 4-wide vector stores
  {
    const int u = ty * 32 + tx;          // 0..255
    const int row = u >> 3, c4 = (u & 7) * 4;
    f16x4 o;
#pragma unroll
    for (int q = 0; q < 4; ++q) o[q] = (_Float16)tile[row][c4 + q];
    *(f16x4*)(xf + ((size_t)b * 2048 + j0 + row) * 768 + c0 + c4) = o;
  }
  // transposed f16
  _Float16* xTb = xT + (size_t)b * 768 * 2048;
#pragma unroll
  for (int dy = 0; dy < 32; dy += 8)
    xTb[(size_t)(c0 + ty + dy) * 2048 + j0 + tx] = (_Float16)tile[tx][ty + dy];
}

extern "C" void kernel_launch(void* const* d_in, const int* in_sizes, int n_in,
                              void* d_out, int out_size, void* d_ws, size_t ws_size,
                              hipStream_t stream) {
  const float* x  = (const float*)d_in[0];
  const float* Wk = (const float*)d_in[1];
  const float* bk = (const float*)d_in[2];
  const float* Wq = (const float*)d_in[3];
  const float* bq = (const float*)d_in[4];
  const float* W1 = (const float*)d_in[5];
  const float* W2 = (const float*)d_in[6];
  float* out = (float*)d_out;

  // ---- ws layout (~168 MiB peak, under the 192.5 MiB proven-safe bound) ----
  char* ws = (char*)d_ws;
  size_t off = 0;
  auto alloc = [&](size_t bytes) -> char* {
    char* p = ws + off;
    off += (bytes + 255) & ~(size_t)255;
    return p;
  };
  _Float16* xf = (_Float16*)alloc(25165824);   // x f16 row-major
  _Float16* kq = (_Float16*)alloc(50331648);   // [16384][1536] k|q; reused p_f16+c+h
  _Float16* Wf = (_Float16*)alloc(4718592);    // Wkq, W1, W2 f16
  _Float16* E  = (_Float16*)alloc(67108864);   // E' = exp(S - m_chunk) f16
  _Float16* xT = (_Float16*)alloc(25165824);   // x^T f16 [b][c][j] (own buffer)
  float*    pm = (float*)alloc(2097152);       // [8][32][2048] partial max
  float*    pZ = (float*)alloc(2097152);       // [8][32][2048] partial sumexp
  float*    bkq  = (float*)alloc(6144);

  _Float16* Wkqf = Wf;
  _Float16* W1f  = Wf + 2 * 589824;
  _Float16* W2f  = Wf + 3 * 589824;
  _Float16* pf16 = kq;                 // alias after E pass consumed kq
  _Float16* cT   = kq + 12582912;      // c table (1MiB) in dead kq space
  _Float16* hf16 = kq + 12582912;      // FFN1 out overwrites cT after fused PV

  const size_t sKQ = (size_t)2048 * 1536;
  const size_t sS  = (size_t)2048 * 2048;
  const size_t sKV = (size_t)2048 * 768;

  // 1. x prep (f16 + transpose in one pass over x) + weight converts
  xprep<<<dim3(24, 64, 8), dim3(32, 8), 0, stream>>>(x, xf, xT);
  convert_f32_f16<<<288, 256, 0, stream>>>(Wk, Wkqf, 73728);
  convert_f32_f16<<<288, 256, 0, stream>>>(Wq, Wkqf + 589824, 73728);
  convert_f32_f16<<<288, 256, 0, stream>>>(W1, W1f, 73728);
  convert_f32_f16<<<288, 256, 0, stream>>>(W2, W2f, 73728);
  concat_bias<<<6, 256, 0, stream>>>(bk, bq, bkq);

  // 2. merged projection: kq = x * Wkq^T + bkq  (M=16384, N=1536, K=768)
  gemm_kt<0><<<dim3(6, 128, 1), 512, 0, stream>>>(xf, 0, 768, Wkqf, 0, 768,
                                                  nullptr, kq, nullptr, 0, 1536,
                                                  bkq, nullptr, nullptr, nullptr, 768);

  // 3. E pass: S = k q^T; E' = exp(S - m_chunk) f16 + (m,Z) partials
  gemm_kt<4><<<dim3(8, 16, 8), 512, 0, stream>>>(kq, sKQ, 1536, kq + 768, sKQ, 1536,
                                                 pm, E, pZ, sS, 2048,
                                                 nullptr, nullptr, nullptr, nullptr, 768);
  col_final<<<dim3(8, 1, 8), 256, 0, stream>>>(pm, pZ, cT);

  // 4. fused PV: p = x + (E' .* c) x  (M=2048, N=768, K=2048), f16 out only
  gemm_kt<6><<<dim3(3, 16, 8), 512, 0, stream>>>(E, sS, 2048, xT, sKV, 2048,
                                                 nullptr, pf16, nullptr, sKV, 768,
                                                 nullptr, x, nullptr, cT, 2048);

  // 5. FFN1: h = p * W1^T (f16 out; overwrites cT — fused PV done)
  gemm_kt<0><<<dim3(3, 128, 1), 512, 0, stream>>>(pf16, 0, 768, W1f, 0, 768,
                                                  nullptr, hf16, nullptr, 0, 768,
                                                  nullptr, nullptr, nullptr, nullptr, 768);

  // 6. FFN2 + residual + relu: out = (f32)p_f16 + relu(h * W2^T)
  gemm_kt<3><<<dim3(3, 128, 1), 512, 0, stream>>>(hf16, 0, 768, W2f, 0, 768,
                                                  out, nullptr, nullptr, 0, 768,
                                                  nullptr, nullptr, pf16, nullptr, 768);
}